// Round 7
// baseline (2369.789 us; speedup 1.0000x reference)
//
#include <hip/hip_runtime.h>

typedef __attribute__((ext_vector_type(8))) short bf16x8;
typedef __attribute__((ext_vector_type(4))) float f32x4;

#define NBLK 256

// ---------- helpers ----------
__device__ __forceinline__ unsigned short f2bf(float f) {
  unsigned u = __float_as_uint(f);
  unsigned r = u + 0x7fffu + ((u >> 16) & 1u);   // RNE
  return (unsigned short)(r >> 16);
}
__device__ __forceinline__ float bf2f(unsigned short h) {
  return __uint_as_float(((unsigned)h) << 16);
}
__device__ __forceinline__ unsigned pack_split(float f) {
  unsigned short hi = f2bf(f);
  float res = f - bf2f(hi);
  unsigned short lo = f2bf(res);
  return (((unsigned)hi) << 16) | (unsigned)lo;
}
// 8 packed weight dwords (2x uint4) -> hi-frag / lo-frag (weight reg-load only)
__device__ __forceinline__ void unpack2(uint4 a0, uint4 a1, bf16x8& hi, bf16x8& lo) {
  union { bf16x8 v; unsigned u[4]; } H, L;
  H.u[0] = (a0.x >> 16) | (a0.y & 0xffff0000u);
  L.u[0] = (a0.x & 0xffffu) | (a0.y << 16);
  H.u[1] = (a0.z >> 16) | (a0.w & 0xffff0000u);
  L.u[1] = (a0.z & 0xffffu) | (a0.w << 16);
  H.u[2] = (a1.x >> 16) | (a1.y & 0xffff0000u);
  L.u[2] = (a1.x & 0xffffu) | (a1.y << 16);
  H.u[3] = (a1.z >> 16) | (a1.w & 0xffff0000u);
  L.u[3] = (a1.z & 0xffffu) | (a1.w << 16);
  hi = H.v; lo = L.v;
}
union U4B { uint4 u; bf16x8 b; };
__device__ __forceinline__ bf16x8 as_bf(uint4 u) { U4B x; x.u = u; return x.b; }
__device__ __forceinline__ float sigm(float x) { return 1.0f / (1.0f + __expf(-x)); }
__device__ __forceinline__ float tanh_f(float x) { return 1.0f - 2.0f / (__expf(2.0f * x) + 1.0f); }

// ---------- prep (unchanged from r4, verified) ----------
__global__ __launch_bounds__(256) void prep_kernel(
    const float* __restrict__ wih, const float* __restrict__ whh,
    const float* __restrict__ wfc_in, const float* __restrict__ hin,
    unsigned* __restrict__ wreg, unsigned* __restrict__ wfc, unsigned* __restrict__ xinit) {
  for (int e0 = 0; e0 < 8; ++e0) {
    unsigned idx = blockIdx.x * 2048u + (unsigned)e0 * 256u + threadIdx.x;
    if (idx < 16777216u) {
      unsigned wg   = idx >> 16;
      unsigned r    = idx & 65535u;
      unsigned wv   = r >> 13;
      unsigned r2   = r & 8191u;
      unsigned l    = r2 >> 12;
      unsigned r3   = r2 & 4095u;
      unsigned kt   = r3 >> 9;
      unsigned r4   = r3 & 511u;
      unsigned lane = r4 >> 3;
      unsigned e    = r4 & 7u;
      unsigned n = lane & 15u, q = lane >> 4;
      unsigned g = n >> 2, jj = n & 3u;
      unsigned col = (g << 10) + ((wg & 7u) << 7) + ((wg >> 3) << 2) + jj;  // pwid*4+jj
      unsigned kloc = (wv << 7) + ((kt & 3u) << 5) + (q << 3) + e;
      float v = (kt < 4u) ? whh[(l << 22) + (col << 10) + kloc]
                          : wih[(l << 22) + (col << 10) + kloc];
      wreg[idx] = pack_split(v);
    } else if (idx < 17825792u) {            // wfc interleaved-per-chunk
      unsigned i2 = idx - 16777216u;
      unsigned r = i2 >> 10, d = i2 & 1023u;
      unsigned kc = d >> 5, rest = d & 31u;
      unsigned half = rest >> 4, p = rest & 15u;
      const float* src = wfc_in + (r << 10) + (kc << 5) + (p << 1);
      unsigned short h0 = f2bf(src[0]);
      unsigned short h1 = f2bf(src[1]);
      unsigned dwv;
      if (half == 0u) {
        dwv = (unsigned)h0 | ((unsigned)h1 << 16);
      } else {
        unsigned short l0 = f2bf(src[0] - bf2f(h0));
        unsigned short l1 = f2bf(src[1] - bf2f(h1));
        dwv = (unsigned)l0 | ((unsigned)l1 << 16);
      }
      wfc[i2] = dwv;
    } else if (idx < 17891328u) {            // xinit fragment-ordered
      unsigned i3 = idx - 17825792u;
      unsigned kc = i3 >> 11;
      unsigned hl = (i3 >> 10) & 1u;
      unsigned mt = (i3 >> 8) & 3u;
      unsigned ln = (i3 >> 2) & 63u;
      unsigned ep = i3 & 3u;
      unsigned rr = (mt << 4) + (ln & 15u);
      unsigned c0 = (kc << 5) + ((ln >> 4) << 3) + (ep << 1);
      const float* src = hin + (rr << 10) + c0;
      unsigned short h0 = f2bf(src[0]);
      unsigned short h1 = f2bf(src[1]);
      unsigned dwv;
      if (hl == 0u) {
        dwv = (unsigned)h0 | ((unsigned)h1 << 16);
      } else {
        unsigned short l0 = f2bf(src[0] - bf2f(h0));
        unsigned short l1 = f2bf(src[1] - bf2f(h1));
        dwv = (unsigned)l0 | ((unsigned)l1 << 16);
      }
      xinit[i3] = dwv;
    }
  }
}

// ---------- generic grid barrier (initial wreg-alias fence only) ----------
__device__ __forceinline__ void grid_barrier(unsigned* barp, unsigned g,
                                             int wid, int tid) {
  __syncthreads();
  if (wid == 0) {
    if (tid > 0 && tid < NBLK) {
      while (__hip_atomic_load(&barp[512 + tid], __ATOMIC_RELAXED,
                               __HIP_MEMORY_SCOPE_AGENT) < g) {
        __builtin_amdgcn_s_sleep(1);
      }
    }
    __syncthreads();
    if (tid < 8) {
      __hip_atomic_store(&barp[tid << 5], g, __ATOMIC_RELAXED, __HIP_MEMORY_SCOPE_AGENT);
    }
  } else {
    if (tid == 0) {
      __hip_atomic_store(&barp[512 + wid], g, __ATOMIC_RELAXED, __HIP_MEMORY_SCOPE_AGENT);
      while (__hip_atomic_load(&barp[(wid & 7) << 5], __ATOMIC_RELAXED,
                               __HIP_MEMORY_SCOPE_AGENT) < g) {
        __builtin_amdgcn_s_sleep(2);
      }
    }
  }
  __syncthreads();
}

// ---------- main persistent LSTM: BARRIER-FREE dataflow ----------
// Per-chunk ready-counters replace the global barrier.
// r7 fixes r5/r6's COUNTER ALIASING: a slab has 32 chunks (32 cols each,
// 8 producer blocks per chunk, j = pwid>>3 in 0..31), so the counter array
// must hold 32 slots per slab. r5/r6 used a 256-dword slab stride with
// stride-32 slots (only 8 fit) -> slots for chunk>=8 aliased the NEXT slabs'
// counters, and since every pair contributes +8 to an aliased slot, polls
// released early -> stale xs reads. New layout: slot = slab*256 + chunk*8
// dwords (stride-8, 32 chunks/slab, no aliasing, 256 KB total). A wave's 4
// polled counters share one 128B line.
__global__ __launch_bounds__(512, 1) void lstm_main(
    const unsigned* __restrict__ wreg,
    unsigned* __restrict__ h0buf,      // [128] fragment slabs (aliases wreg low half)
    const unsigned* __restrict__ xinit,
    const unsigned* __restrict__ hzero,
    unsigned* __restrict__ rec,        // [128] fragment slabs = h1 history
    const float* __restrict__ bih, const float* __restrict__ bhh,
    unsigned* __restrict__ barp,
    unsigned* __restrict__ cnt) {      // [256 slabs][32 chunks] stride-8 dwords
  __shared__ float part_lds[8][64][16];   // 32 KB partials only

  const int tid = threadIdx.x;
  const int wid = blockIdx.x;
  const int wave = tid >> 6;
  const int lane = tid & 63;
  const int q = lane >> 4;
  const int m16 = lane & 15;
  const int pwid = ((wid & 7) << 5) | (wid >> 3);

  // ---- weight slice -> registers, pin ----
  bf16x8 whi[2][8], wlo[2][8];
  {
    const unsigned* wb = wreg + ((size_t)wid << 16) + ((size_t)wave << 13) + (lane << 3);
    #pragma unroll
    for (int l = 0; l < 2; ++l)
      #pragma unroll
      for (int kt = 0; kt < 8; ++kt) {
        const unsigned* p = wb + (l << 12) + (kt << 9);
        uint4 a0 = *(const uint4*)p;
        uint4 a1 = *(const uint4*)(p + 4);
        unpack2(a0, a1, whi[l][kt], wlo[l][kt]);
      }
    #pragma unroll
    for (int l = 0; l < 2; ++l)
      #pragma unroll
      for (int kt = 0; kt < 8; ++kt) {
        asm volatile("" : "+v"(whi[l][kt]), "+v"(wlo[l][kt]));
      }
  }

  // EW thread state (threads 0..255 own (b=tid>>2, jj=tid&3))
  const int eb = tid >> 2;
  const int ej = tid & 3;
  float creg[2] = {0.0f, 0.0f};
  float biasr[2][4] = {{0, 0, 0, 0}, {0, 0, 0, 0}};
  if (tid < 256) {
    #pragma unroll
    for (int l = 0; l < 2; ++l)
      #pragma unroll
      for (int g = 0; g < 4; ++g) {
        int col = (g << 10) + (pwid << 2) + ej;
        biasr[l][g] = bih[(l << 12) + col] + bhh[(l << 12) + col];
      }
  }

  // all blocks done reading wreg (h0buf aliases it) + one-time acquire
  grid_barrier(barp, 1u, wid, tid);
  __builtin_amdgcn_fence(__ATOMIC_ACQUIRE, "agent");

  // per-lane slab byte base: chunk (wave*4+j): + j<<13 ; mt: + mt<<10 ; lo: +4096
  const unsigned abase = ((unsigned)wave << 15) + ((unsigned)lane << 4);
  const int pcol = ((m16 & 3) << 2) | (m16 >> 2);  // partials col perm (b128 reduce)
  const f32x4 fzero = {0.0f, 0.0f, 0.0f, 0.0f};
  // this wave's 4 xs-chunk counters (chunks 4*wave .. 4*wave+3), stride-8 slots;
  // lanes 0-3 cover them (other lanes duplicate)
  unsigned* const cpoll = cnt + (((wave << 2) + (lane & 3)) << 3);
  // producer: this block contributes to chunk pwid>>3
  unsigned* const cadd = cnt + ((pwid >> 3) << 3);

  uint4 fh[2][4], fl[2][4];  // 2-slot fragment ring (static indices only)

  #define LOADC(slot_, srcp_, j_)                                              \
    { _Pragma("unroll")                                                        \
      for (int mtq = 0; mtq < 4; ++mtq) {                                      \
        const char* pb = (const char*)(srcp_) + abase + ((j_) << 13) + (mtq << 10); \
        fh[slot_][mtq] = *(const uint4*)pb;                                    \
        fl[slot_][mtq] = *(const uint4*)(pb + 4096);                           \
      } }

  #define MFMA3(accv_, sl_, L_, KW_)                                           \
    { _Pragma("unroll")                                                        \
      for (int mtq = 0; mtq < 4; ++mtq) {                                      \
        bf16x8 ah = as_bf(fh[sl_][mtq]);                                       \
        bf16x8 al = as_bf(fl[sl_][mtq]);                                       \
        accv_[mtq] = __builtin_amdgcn_mfma_f32_16x16x32_bf16(ah, whi[L_][KW_], accv_[mtq], 0, 0, 0); \
        accv_[mtq] = __builtin_amdgcn_mfma_f32_16x16x32_bf16(ah, wlo[L_][KW_], accv_[mtq], 0, 0, 0); \
        accv_[mtq] = __builtin_amdgcn_mfma_f32_16x16x32_bf16(al, whi[L_][KW_], accv_[mtq], 0, 0, 0); \
      } }

  for (int t = 0; t < 128; ++t) {
    #pragma unroll
    for (int l = 0; l < 2; ++l) {
      const unsigned* srcx;
      const unsigned* srch;
      unsigned* dst;
      int xsid, addid;
      if (l == 0) {
        srcx = (t == 0) ? xinit : rec + ((t - 1) << 16);
        srch = (t == 0) ? hzero : h0buf + ((t - 1) << 16);
        dst  = h0buf + (t << 16);
        xsid = 128 + t - 1;      // only used when t>0
        addid = t;
      } else {
        srcx = h0buf + (t << 16);
        srch = (t == 0) ? hzero : rec + ((t - 1) << 16);
        dst  = rec + (t << 16);
        xsid = t;
        addid = 128 + t;
      }
      const bool pollx = (l == 1) || (t > 0);

      f32x4 acc[4];
      #pragma unroll
      for (int mt = 0; mt < 4; ++mt) acc[mt] = fzero;

      // ---- hs half first (no poll: verified as xs of a previous phase) ----
      LOADC(0, srch, 0)
      LOADC(1, srch, 1)
      MFMA3(acc, 0, l, 0)
      LOADC(0, srch, 2)
      MFMA3(acc, 1, l, 1)
      LOADC(1, srch, 3)

      // ---- xs readiness: poll this wave's 4 chunk counters ----
      if (pollx) {
        const unsigned* cp = cpoll + (xsid << 8);
        unsigned cv;
        do {
          cv = __hip_atomic_load(cp, __ATOMIC_RELAXED, __HIP_MEMORY_SCOPE_AGENT);
          if (!__ballot(cv < 8u)) break;
          __builtin_amdgcn_s_sleep(1);
        } while (true);
        // COMPILER FENCE: the xs loads below must not be hoisted above the
        // poll. HW side safe: control dependency + write-once slabs.
        asm volatile("" ::: "memory");
      }

      MFMA3(acc, 0, l, 2)
      LOADC(0, srcx, 0)
      MFMA3(acc, 1, l, 3)
      LOADC(1, srcx, 1)
      MFMA3(acc, 0, l, 4)
      LOADC(0, srcx, 2)
      MFMA3(acc, 1, l, 5)
      LOADC(1, srcx, 3)
      MFMA3(acc, 0, l, 6)
      MFMA3(acc, 1, l, 7)

      // ---- partials -> LDS ----
      #pragma unroll
      for (int mt = 0; mt < 4; ++mt)
        #pragma unroll
        for (int r = 0; r < 4; ++r)
          part_lds[wave][(mt << 4) + (q << 2) + r][pcol] = acc[mt][r];
      asm volatile("s_waitcnt lgkmcnt(0)" ::: "memory");
      __builtin_amdgcn_s_barrier();      // A1: partials visible
      asm volatile("" ::: "memory");

      // ---- reduce + elementwise + publish ----
      if (tid < 256) {
        f32x4 s4 = {biasr[l][0], biasr[l][1], biasr[l][2], biasr[l][3]};
        #pragma unroll
        for (int w = 0; w < 8; ++w)
          s4 += *(const f32x4*)&part_lds[w][eb][ej << 2];
        float ig = sigm(s4.x);
        float fg = sigm(s4.y);
        float gv = tanh_f(s4.z);
        float og = sigm(s4.w);
        float cn = fg * creg[l] + ig * gv;
        float hn = og * tanh_f(cn);
        creg[l] = cn;
        unsigned hiv = f2bf(hn);
        unsigned lov = f2bf(hn - bf2f((unsigned short)hiv));
        unsigned phi = __shfl_xor(hiv, 1);
        unsigned plo = __shfl_xor(lov, 1);
        unsigned dw = (ej & 1) ? (plo | (lov << 16)) : (hiv | (phi << 16));
        int idx = ((pwid >> 3) << 11) + ((ej & 1) << 10) + ((eb >> 4) << 8)
                + (((((pwid & 7) >> 1) << 4) + (eb & 15)) << 2)
                + ((pwid & 1) << 1) + (ej >> 1);
        __hip_atomic_store(&dst[idx], dw, __ATOMIC_RELAXED, __HIP_MEMORY_SCOPE_AGENT);
        // drain own publish store (per-wave vmcnt; waves 4-7 unaffected)
        asm volatile("s_waitcnt vmcnt(0)" ::: "memory");
      }
      asm volatile("" ::: "memory");
      __builtin_amdgcn_s_barrier();      // A2: all 256 publish stores drained
      asm volatile("" ::: "memory");

      // ---- signal chunk readiness: one RELEASE add per block per phase ----
      if (tid == 0) {
        (void)__hip_atomic_fetch_add(&cadd[addid << 8], 1u, __ATOMIC_RELEASE,
                                     __HIP_MEMORY_SCOPE_AGENT);
      }
    }
  }
  #undef LOADC
  #undef MFMA3
}

// ---------- FC: out[8192,1024] = rec @ Wfc^T + b_fc (unchanged from r4) ----------
__global__ __launch_bounds__(256) void fc_kernel(
    const unsigned* __restrict__ rec, const unsigned* __restrict__ wfc,
    const float* __restrict__ bfc, float* __restrict__ out) {
  __shared__ unsigned w_lds[128 * 36];
  const int tid = threadIdx.x;
  const int wave = tid >> 6;
  const int lane = tid & 63;
  const int q = lane >> 4;
  const int m16 = lane & 15;
  const int m0 = (blockIdx.x >> 3) << 7;
  const int n0 = (blockIdx.x & 7) << 7;
  const f32x4 fzero = {0.0f, 0.0f, 0.0f, 0.0f};

  f32x4 acc[2][8];
  for (int mt = 0; mt < 2; ++mt)
    for (int nt = 0; nt < 8; ++nt) acc[mt][nt] = fzero;

  for (int kc = 0; kc < 32; ++kc) {
    __syncthreads();
    #pragma unroll
    for (int i = 0; i < 4; ++i) {
      int c = (i << 8) + tid;
      int r = c >> 3;
      int cc = (c & 7) << 2;
      *(uint4*)(w_lds + r * 36 + cc) = *(const uint4*)(wfc + ((n0 + r) << 10) + (kc << 5) + cc);
    }
    __syncthreads();

    bf16x8 ahi[2], alo[2];
    #pragma unroll
    for (int mtl = 0; mtl < 2; ++mtl) {
      int grow = m0 + (wave << 5) + (mtl << 4);
      const char* ab = (const char*)rec + ((size_t)(grow >> 6) << 18)
                     + ((size_t)kc << 13) + (((grow >> 4) & 3) << 10) + (lane << 4);
      ahi[mtl] = as_bf(*(const uint4*)ab);
      alo[mtl] = as_bf(*(const uint4*)(ab + 4096));
    }
    #pragma unroll
    for (int nt = 0; nt < 8; ++nt) {
      int wrow = (nt << 4) + m16;
      bf16x8 bhi = as_bf(*(const uint4*)(w_lds + wrow * 36 + (q << 2)));
      bf16x8 blo = as_bf(*(const uint4*)(w_lds + wrow * 36 + 16 + (q << 2)));
      #pragma unroll
      for (int mt = 0; mt < 2; ++mt) {
        acc[mt][nt] = __builtin_amdgcn_mfma_f32_16x16x32_bf16(ahi[mt], bhi, acc[mt][nt], 0, 0, 0);
        acc[mt][nt] = __builtin_amdgcn_mfma_f32_16x16x32_bf16(ahi[mt], blo, acc[mt][nt], 0, 0, 0);
        acc[mt][nt] = __builtin_amdgcn_mfma_f32_16x16x32_bf16(alo[mt], bhi, acc[mt][nt], 0, 0, 0);
      }
    }
  }
  #pragma unroll
  for (int mt = 0; mt < 2; ++mt)
    #pragma unroll
    for (int nt = 0; nt < 8; ++nt) {
      int n = n0 + (nt << 4) + m16;
      float bv = bfc[n];
      #pragma unroll
      for (int r2 = 0; r2 < 4; ++r2) {
        int m = m0 + (wave << 5) + (mt << 4) + (q << 2) + r2;
        out[(m << 10) + n] = acc[mt][nt][r2] + bv;
      }
    }
}

// ---------- launch ----------
extern "C" void kernel_launch(void* const* d_in, const int* in_sizes, int n_in,
                              void* d_out, int out_size, void* d_ws, size_t ws_size,
                              hipStream_t stream) {
  const float* h_in = (const float*)d_in[0];
  const float* W_ih = (const float*)d_in[1];
  const float* W_hh = (const float*)d_in[2];
  const float* b_ih = (const float*)d_in[3];
  const float* b_hh = (const float*)d_in[4];
  const float* W_fc = (const float*)d_in[5];
  const float* b_fc = (const float*)d_in[6];
  (void)in_sizes; (void)n_in; (void)out_size; (void)ws_size;

  char* ws = (char*)d_ws;
  unsigned* wreg  = (unsigned*)(ws + 0);          // 64 MB
  unsigned* h0buf = (unsigned*)(ws + 0);          // 32 MB, aliases wreg lower half
  unsigned* wfc   = (unsigned*)(ws + 67108864);   // 4 MB (interleaved)
  unsigned* xinit = (unsigned*)(ws + 71303168);   // 256 KB (fragment-ordered)
  unsigned* hzero = (unsigned*)(ws + 71565312);   // 256 KB zeros
  unsigned* barp  = (unsigned*)(ws + 71827456);   // 8 KB: initial-barrier gens+flags
  unsigned* cnt   = (unsigned*)(ws + 71835648);   // 256 KB: [256 slabs][32 chunks] stride-8
  unsigned* rec   = (unsigned*)(ws + 72616192);   // 32 MB (fragment-ordered)
  float*    out   = (float*)d_out;

  // zero: hzero + barp + cnt (contiguous region 71565312 .. 72097792)
  (void)hipMemsetAsync(ws + 71565312, 0, 532480, stream);

  prep_kernel<<<dim3(8736), dim3(256), 0, stream>>>(W_ih, W_hh, W_fc, h_in,
                                                    wreg, wfc, xinit);

  lstm_main<<<dim3(NBLK), dim3(512), 0, stream>>>(wreg, h0buf, xinit, hzero, rec,
                                                  b_ih, b_hh, barp, cnt);

  fc_kernel<<<dim3(512), dim3(256), 0, stream>>>(rec, wfc, b_fc, out);
}

// Round 8
// 1778.166 us; speedup vs baseline: 1.3327x; 1.3327x over previous
//
#include <hip/hip_runtime.h>

typedef __attribute__((ext_vector_type(8))) short bf16x8;
typedef __attribute__((ext_vector_type(4))) float f32x4;

#define NBLK 256

// ---------- helpers ----------
__device__ __forceinline__ unsigned short f2bf(float f) {
  unsigned u = __float_as_uint(f);
  unsigned r = u + 0x7fffu + ((u >> 16) & 1u);   // RNE
  return (unsigned short)(r >> 16);
}
__device__ __forceinline__ float bf2f(unsigned short h) {
  return __uint_as_float(((unsigned)h) << 16);
}
__device__ __forceinline__ unsigned pack_split(float f) {
  unsigned short hi = f2bf(f);
  float res = f - bf2f(hi);
  unsigned short lo = f2bf(res);
  return (((unsigned)hi) << 16) | (unsigned)lo;
}
// 8 packed weight dwords (2x uint4) -> hi-frag / lo-frag (weight reg-load only)
__device__ __forceinline__ void unpack2(uint4 a0, uint4 a1, bf16x8& hi, bf16x8& lo) {
  union { bf16x8 v; unsigned u[4]; } H, L;
  H.u[0] = (a0.x >> 16) | (a0.y & 0xffff0000u);
  L.u[0] = (a0.x & 0xffffu) | (a0.y << 16);
  H.u[1] = (a0.z >> 16) | (a0.w & 0xffff0000u);
  L.u[1] = (a0.z & 0xffffu) | (a0.w << 16);
  H.u[2] = (a1.x >> 16) | (a1.y & 0xffff0000u);
  L.u[2] = (a1.x & 0xffffu) | (a1.y << 16);
  H.u[3] = (a1.z >> 16) | (a1.w & 0xffff0000u);
  L.u[3] = (a1.z & 0xffffu) | (a1.w << 16);
  hi = H.v; lo = L.v;
}
union U4B { uint4 u; bf16x8 b; };
__device__ __forceinline__ bf16x8 as_bf(uint4 u) { U4B x; x.u = u; return x.b; }
__device__ __forceinline__ float sigm(float x) { return 1.0f / (1.0f + __expf(-x)); }
__device__ __forceinline__ float tanh_f(float x) { return 1.0f - 2.0f / (__expf(2.0f * x) + 1.0f); }

// ---------- prep (unchanged from r4, verified) ----------
__global__ __launch_bounds__(256) void prep_kernel(
    const float* __restrict__ wih, const float* __restrict__ whh,
    const float* __restrict__ wfc_in, const float* __restrict__ hin,
    unsigned* __restrict__ wreg, unsigned* __restrict__ wfc, unsigned* __restrict__ xinit) {
  for (int e0 = 0; e0 < 8; ++e0) {
    unsigned idx = blockIdx.x * 2048u + (unsigned)e0 * 256u + threadIdx.x;
    if (idx < 16777216u) {
      unsigned wg   = idx >> 16;
      unsigned r    = idx & 65535u;
      unsigned wv   = r >> 13;
      unsigned r2   = r & 8191u;
      unsigned l    = r2 >> 12;
      unsigned r3   = r2 & 4095u;
      unsigned kt   = r3 >> 9;
      unsigned r4   = r3 & 511u;
      unsigned lane = r4 >> 3;
      unsigned e    = r4 & 7u;
      unsigned n = lane & 15u, q = lane >> 4;
      unsigned g = n >> 2, jj = n & 3u;
      unsigned col = (g << 10) + ((wg & 7u) << 7) + ((wg >> 3) << 2) + jj;  // pwid*4+jj
      unsigned kloc = (wv << 7) + ((kt & 3u) << 5) + (q << 3) + e;
      float v = (kt < 4u) ? whh[(l << 22) + (col << 10) + kloc]
                          : wih[(l << 22) + (col << 10) + kloc];
      wreg[idx] = pack_split(v);
    } else if (idx < 17825792u) {            // wfc interleaved-per-chunk
      unsigned i2 = idx - 16777216u;
      unsigned r = i2 >> 10, d = i2 & 1023u;
      unsigned kc = d >> 5, rest = d & 31u;
      unsigned half = rest >> 4, p = rest & 15u;
      const float* src = wfc_in + (r << 10) + (kc << 5) + (p << 1);
      unsigned short h0 = f2bf(src[0]);
      unsigned short h1 = f2bf(src[1]);
      unsigned dwv;
      if (half == 0u) {
        dwv = (unsigned)h0 | ((unsigned)h1 << 16);
      } else {
        unsigned short l0 = f2bf(src[0] - bf2f(h0));
        unsigned short l1 = f2bf(src[1] - bf2f(h1));
        dwv = (unsigned)l0 | ((unsigned)l1 << 16);
      }
      wfc[i2] = dwv;
    } else if (idx < 17891328u) {            // xinit fragment-ordered
      unsigned i3 = idx - 17825792u;
      unsigned kc = i3 >> 11;
      unsigned hl = (i3 >> 10) & 1u;
      unsigned mt = (i3 >> 8) & 3u;
      unsigned ln = (i3 >> 2) & 63u;
      unsigned ep = i3 & 3u;
      unsigned rr = (mt << 4) + (ln & 15u);
      unsigned c0 = (kc << 5) + ((ln >> 4) << 3) + (ep << 1);
      const float* src = hin + (rr << 10) + c0;
      unsigned short h0 = f2bf(src[0]);
      unsigned short h1 = f2bf(src[1]);
      unsigned dwv;
      if (hl == 0u) {
        dwv = (unsigned)h0 | ((unsigned)h1 << 16);
      } else {
        unsigned short l0 = f2bf(src[0] - bf2f(h0));
        unsigned short l1 = f2bf(src[1] - bf2f(h1));
        dwv = (unsigned)l0 | ((unsigned)l1 << 16);
      }
      xinit[i3] = dwv;
    }
  }
}

// ---------- generic grid barrier (initial wreg-alias fence only) ----------
__device__ __forceinline__ void grid_barrier(unsigned* barp, unsigned g,
                                             int wid, int tid) {
  __syncthreads();
  if (wid == 0) {
    if (tid > 0 && tid < NBLK) {
      while (__hip_atomic_load(&barp[512 + tid], __ATOMIC_RELAXED,
                               __HIP_MEMORY_SCOPE_AGENT) < g) {
        __builtin_amdgcn_s_sleep(1);
      }
    }
    __syncthreads();
    if (tid < 8) {
      __hip_atomic_store(&barp[tid << 5], g, __ATOMIC_RELAXED, __HIP_MEMORY_SCOPE_AGENT);
    }
  } else {
    if (tid == 0) {
      __hip_atomic_store(&barp[512 + wid], g, __ATOMIC_RELAXED, __HIP_MEMORY_SCOPE_AGENT);
      while (__hip_atomic_load(&barp[(wid & 7) << 5], __ATOMIC_RELAXED,
                               __HIP_MEMORY_SCOPE_AGENT) < g) {
        __builtin_amdgcn_s_sleep(2);
      }
    }
  }
  __syncthreads();
}

// ---------- main persistent LSTM ----------
// r8 = r4 barrier skeleton + KEY INVARIANT: next phase's hs slab == current
// phase's xs slab ((t,0):xs=rec[t-1]=(t,1):hs ; (t,1):xs=h0[t]=(t+1,0):hs).
// So xs fragments are RETAINED in a 4-slot register ring across the phase
// boundary and the hs half (acch, computed under the barrier wait) needs ZERO
// loads. Halves per-block L2 reads (512->256 KB/phase) and deletes hs load
// latency. t=0 phases have hs=0 -> skip acch MFMAs ((0,0) tail guarded).
__global__ __launch_bounds__(512, 1) void lstm_main(
    const unsigned* __restrict__ wreg,
    unsigned* __restrict__ h0buf,      // [128] fragment slabs (aliases wreg low half)
    const unsigned* __restrict__ xinit,
    unsigned* __restrict__ rec,        // [128] fragment slabs = h1 history
    const float* __restrict__ bih, const float* __restrict__ bhh,
    unsigned* __restrict__ barp) {
  __shared__ float part_lds[8][64][16];   // 32 KB partials only

  const int tid = threadIdx.x;
  const int wid = blockIdx.x;
  const int wave = tid >> 6;
  const int lane = tid & 63;
  const int q = lane >> 4;
  const int m16 = lane & 15;
  const int pwid = ((wid & 7) << 5) | (wid >> 3);

  // ---- weight slice -> registers, pin ----
  bf16x8 whi[2][8], wlo[2][8];
  {
    const unsigned* wb = wreg + ((size_t)wid << 16) + ((size_t)wave << 13) + (lane << 3);
    #pragma unroll
    for (int l = 0; l < 2; ++l)
      #pragma unroll
      for (int kt = 0; kt < 8; ++kt) {
        const unsigned* p = wb + (l << 12) + (kt << 9);
        uint4 a0 = *(const uint4*)p;
        uint4 a1 = *(const uint4*)(p + 4);
        unpack2(a0, a1, whi[l][kt], wlo[l][kt]);
      }
    #pragma unroll
    for (int l = 0; l < 2; ++l)
      #pragma unroll
      for (int kt = 0; kt < 8; ++kt) {
        asm volatile("" : "+v"(whi[l][kt]), "+v"(wlo[l][kt]));
      }
  }

  // EW thread state (threads 0..255 own (b=tid>>2, jj=tid&3))
  const int eb = tid >> 2;
  const int ej = tid & 3;
  float creg[2] = {0.0f, 0.0f};
  float biasr[2][4] = {{0, 0, 0, 0}, {0, 0, 0, 0}};
  if (tid < 256) {
    #pragma unroll
    for (int l = 0; l < 2; ++l)
      #pragma unroll
      for (int g = 0; g < 4; ++g) {
        int col = (g << 10) + (pwid << 2) + ej;
        biasr[l][g] = bih[(l << 12) + col] + bhh[(l << 12) + col];
      }
  }

  // all blocks done reading wreg (h0buf aliases it) + one-time acquire
  grid_barrier(barp, 1u, wid, tid);
  __builtin_amdgcn_fence(__ATOMIC_ACQUIRE, "agent");

  // per-lane slab byte base: chunk (wave*4+j): + j<<13 ; mt: + mt<<10 ; lo: +4096
  const unsigned abase = ((unsigned)wave << 15) + ((unsigned)lane << 4);
  const int pcol = ((m16 & 3) << 2) | (m16 >> 2);  // partials col perm (b128 reduce)
  const f32x4 fzero = {0.0f, 0.0f, 0.0f, 0.0f};

  uint4 fh[4][4], fl[4][4];  // 4-slot fragment ring, retained across phases

  #define LOADC(slot_, srcp_, j_)                                              \
    { _Pragma("unroll")                                                        \
      for (int mtq = 0; mtq < 4; ++mtq) {                                      \
        const char* pb = (const char*)(srcp_) + abase + ((j_) << 13) + (mtq << 10); \
        fh[slot_][mtq] = *(const uint4*)pb;                                    \
        fl[slot_][mtq] = *(const uint4*)(pb + 4096);                           \
      } }

  #define MFMA3(accv_, sl_, L_, KW_)                                           \
    { _Pragma("unroll")                                                        \
      for (int mtq = 0; mtq < 4; ++mtq) {                                      \
        bf16x8 ah = as_bf(fh[sl_][mtq]);                                       \
        bf16x8 al = as_bf(fl[sl_][mtq]);                                       \
        accv_[mtq] = __builtin_amdgcn_mfma_f32_16x16x32_bf16(ah, whi[L_][KW_], accv_[mtq], 0, 0, 0); \
        accv_[mtq] = __builtin_amdgcn_mfma_f32_16x16x32_bf16(ah, wlo[L_][KW_], accv_[mtq], 0, 0, 0); \
        accv_[mtq] = __builtin_amdgcn_mfma_f32_16x16x32_bf16(al, whi[L_][KW_], accv_[mtq], 0, 0, 0); \
      } }

  // hs-partials of the upcoming phase; (0,0) has h=0 -> zero
  f32x4 acch[4];
  #pragma unroll
  for (int mt = 0; mt < 4; ++mt) acch[mt] = fzero;

  for (int t = 0; t < 128; ++t) {
    #pragma unroll
    for (int l = 0; l < 2; ++l) {
      const unsigned* srcx;
      unsigned* dst;
      if (l == 0) {
        srcx = (t == 0) ? xinit : rec + ((t - 1) << 16);
        dst = h0buf + (t << 16);
      } else {
        srcx = h0buf + (t << 16);
        dst = rec + (t << 16);
      }
      const bool last = (t == 127) && (l == 1);

      // ---- xs half: acc = acch + x @ W_ih^T slice (4 slots, loads up front) ----
      f32x4 acc[4];
      #pragma unroll
      for (int mt = 0; mt < 4; ++mt) acc[mt] = acch[mt];

      LOADC(0, srcx, 0)
      LOADC(1, srcx, 1)
      LOADC(2, srcx, 2)
      LOADC(3, srcx, 3)
      MFMA3(acc, 0, l, 4)
      MFMA3(acc, 1, l, 5)
      MFMA3(acc, 2, l, 6)
      MFMA3(acc, 3, l, 7)

      // ---- partials -> LDS ----
      #pragma unroll
      for (int mt = 0; mt < 4; ++mt)
        #pragma unroll
        for (int r = 0; r < 4; ++r)
          part_lds[wave][(mt << 4) + (q << 2) + r][pcol] = acc[mt][r];
      asm volatile("s_waitcnt lgkmcnt(0)" ::: "memory");
      __builtin_amdgcn_s_barrier();      // A1: partials visible
      asm volatile("" ::: "memory");

      // ---- reduce + elementwise + publish ----
      if (tid < 256) {
        f32x4 s4 = {biasr[l][0], biasr[l][1], biasr[l][2], biasr[l][3]};
        #pragma unroll
        for (int w = 0; w < 8; ++w)
          s4 += *(const f32x4*)&part_lds[w][eb][ej << 2];
        float ig = sigm(s4.x);
        float fg = sigm(s4.y);
        float gv = tanh_f(s4.z);
        float og = sigm(s4.w);
        float cn = fg * creg[l] + ig * gv;
        float hn = og * tanh_f(cn);
        creg[l] = cn;
        unsigned hiv = f2bf(hn);
        unsigned lov = f2bf(hn - bf2f((unsigned short)hiv));
        unsigned phi = __shfl_xor(hiv, 1);
        unsigned plo = __shfl_xor(lov, 1);
        unsigned dw = (ej & 1) ? (plo | (lov << 16)) : (hiv | (phi << 16));
        int idx = ((pwid >> 3) << 11) + ((ej & 1) << 10) + ((eb >> 4) << 8)
                + (((((pwid & 7) >> 1) << 4) + (eb & 15)) << 2)
                + ((pwid & 1) << 1) + (ej >> 1);
        __hip_atomic_store(&dst[idx], dw, __ATOMIC_RELAXED, __HIP_MEMORY_SCOPE_AGENT);
        // drain own publish store (per-wave vmcnt; waves 4-7 unaffected)
        asm volatile("s_waitcnt vmcnt(0)" ::: "memory");
      }
      if (last) return;

      asm volatile("" ::: "memory");
      __builtin_amdgcn_s_barrier();      // A2: all publishes drained
      asm volatile("" ::: "memory");

      const unsigned gph = (unsigned)(2 * t + l + 2);
      if (wid != 0 && tid == 0) {
        __hip_atomic_store(&barp[512 + wid], gph, __ATOMIC_RELAXED,
                           __HIP_MEMORY_SCOPE_AGENT);
      }

      // ---- hs precompute for next phase from RETAINED xs regs (no loads!) ----
      // next hs slab == this phase's xs slab; weights: W_hh of layer l^1.
      // Exception: tail of (0,0): next phase (0,1) has hs=0 -> keep acch=0.
      #pragma unroll
      for (int mt = 0; mt < 4; ++mt) acch[mt] = fzero;
      if (!(t == 0 && l == 0)) {
        MFMA3(acch, 0, l ^ 1, 0)
        MFMA3(acch, 1, l ^ 1, 1)
        MFMA3(acch, 2, l ^ 1, 2)
        MFMA3(acch, 3, l ^ 1, 3)
      }

      // ---- release ----
      if (wid == 0) {
        if (tid > 0 && tid < NBLK) {
          while (__hip_atomic_load(&barp[512 + tid], __ATOMIC_RELAXED,
                                   __HIP_MEMORY_SCOPE_AGENT) < gph) {
            __builtin_amdgcn_s_sleep(1);
          }
        }
        asm volatile("" ::: "memory");
        __builtin_amdgcn_s_barrier();
        asm volatile("" ::: "memory");
        if (tid < 8) {
          __hip_atomic_store(&barp[tid << 5], gph, __ATOMIC_RELAXED,
                             __HIP_MEMORY_SCOPE_AGENT);
        }
      } else {
        if (tid == 0) {
          while (__hip_atomic_load(&barp[(wid & 7) << 5], __ATOMIC_RELAXED,
                                   __HIP_MEMORY_SCOPE_AGENT) < gph) {
            __builtin_amdgcn_s_sleep(2);
          }
        }
      }
      asm volatile("" ::: "memory");
      __builtin_amdgcn_s_barrier();      // B: release
      asm volatile("" ::: "memory");
    }
  }
  #undef LOADC
  #undef MFMA3
}

// ---------- FC: out[8192,1024] = rec @ Wfc^T + b_fc (unchanged from r4) ----------
__global__ __launch_bounds__(256) void fc_kernel(
    const unsigned* __restrict__ rec, const unsigned* __restrict__ wfc,
    const float* __restrict__ bfc, float* __restrict__ out) {
  __shared__ unsigned w_lds[128 * 36];
  const int tid = threadIdx.x;
  const int wave = tid >> 6;
  const int lane = tid & 63;
  const int q = lane >> 4;
  const int m16 = lane & 15;
  const int m0 = (blockIdx.x >> 3) << 7;
  const int n0 = (blockIdx.x & 7) << 7;
  const f32x4 fzero = {0.0f, 0.0f, 0.0f, 0.0f};

  f32x4 acc[2][8];
  for (int mt = 0; mt < 2; ++mt)
    for (int nt = 0; nt < 8; ++nt) acc[mt][nt] = fzero;

  for (int kc = 0; kc < 32; ++kc) {
    __syncthreads();
    #pragma unroll
    for (int i = 0; i < 4; ++i) {
      int c = (i << 8) + tid;
      int r = c >> 3;
      int cc = (c & 7) << 2;
      *(uint4*)(w_lds + r * 36 + cc) = *(const uint4*)(wfc + ((n0 + r) << 10) + (kc << 5) + cc);
    }
    __syncthreads();

    bf16x8 ahi[2], alo[2];
    #pragma unroll
    for (int mtl = 0; mtl < 2; ++mtl) {
      int grow = m0 + (wave << 5) + (mtl << 4);
      const char* ab = (const char*)rec + ((size_t)(grow >> 6) << 18)
                     + ((size_t)kc << 13) + (((grow >> 4) & 3) << 10) + (lane << 4);
      ahi[mtl] = as_bf(*(const uint4*)ab);
      alo[mtl] = as_bf(*(const uint4*)(ab + 4096));
    }
    #pragma unroll
    for (int nt = 0; nt < 8; ++nt) {
      int wrow = (nt << 4) + m16;
      bf16x8 bhi = as_bf(*(const uint4*)(w_lds + wrow * 36 + (q << 2)));
      bf16x8 blo = as_bf(*(const uint4*)(w_lds + wrow * 36 + 16 + (q << 2)));
      #pragma unroll
      for (int mt = 0; mt < 2; ++mt) {
        acc[mt][nt] = __builtin_amdgcn_mfma_f32_16x16x32_bf16(ahi[mt], bhi, acc[mt][nt], 0, 0, 0);
        acc[mt][nt] = __builtin_amdgcn_mfma_f32_16x16x32_bf16(ahi[mt], blo, acc[mt][nt], 0, 0, 0);
        acc[mt][nt] = __builtin_amdgcn_mfma_f32_16x16x32_bf16(alo[mt], bhi, acc[mt][nt], 0, 0, 0);
      }
    }
  }
  #pragma unroll
  for (int mt = 0; mt < 2; ++mt)
    #pragma unroll
    for (int nt = 0; nt < 8; ++nt) {
      int n = n0 + (nt << 4) + m16;
      float bv = bfc[n];
      #pragma unroll
      for (int r2 = 0; r2 < 4; ++r2) {
        int m = m0 + (wave << 5) + (mt << 4) + (q << 2) + r2;
        out[(m << 10) + n] = acc[mt][nt][r2] + bv;
      }
    }
}

// ---------- launch ----------
extern "C" void kernel_launch(void* const* d_in, const int* in_sizes, int n_in,
                              void* d_out, int out_size, void* d_ws, size_t ws_size,
                              hipStream_t stream) {
  const float* h_in = (const float*)d_in[0];
  const float* W_ih = (const float*)d_in[1];
  const float* W_hh = (const float*)d_in[2];
  const float* b_ih = (const float*)d_in[3];
  const float* b_hh = (const float*)d_in[4];
  const float* W_fc = (const float*)d_in[5];
  const float* b_fc = (const float*)d_in[6];
  (void)in_sizes; (void)n_in; (void)out_size; (void)ws_size;

  char* ws = (char*)d_ws;
  unsigned* wreg  = (unsigned*)(ws + 0);          // 64 MB
  unsigned* h0buf = (unsigned*)(ws + 0);          // 32 MB, aliases wreg lower half
  unsigned* wfc   = (unsigned*)(ws + 67108864);   // 4 MB (interleaved)
  unsigned* xinit = (unsigned*)(ws + 71303168);   // 256 KB (fragment-ordered)
  unsigned* barp  = (unsigned*)(ws + 71827456);   // 8 KB: barrier gens+flags
  unsigned* rec   = (unsigned*)(ws + 72616192);   // 32 MB (fragment-ordered)
  float*    out   = (float*)d_out;

  // zero the sync region (covers barp; harmlessly wider)
  (void)hipMemsetAsync(ws + 71565312, 0, 532480, stream);

  prep_kernel<<<dim3(8736), dim3(256), 0, stream>>>(W_ih, W_hh, W_fc, h_in,
                                                    wreg, wfc, xinit);

  lstm_main<<<dim3(NBLK), dim3(512), 0, stream>>>(wreg, h0buf, xinit, rec,
                                                  b_ih, b_hh, barp);

  fc_kernel<<<dim3(512), dim3(256), 0, stream>>>(rec, wfc, b_fc, out);
}